// Round 11
// baseline (1255.280 us; speedup 1.0000x reference)
//
#include <hip/hip_runtime.h>
#include <stdint.h>

namespace {

constexpr int   B_    = 64;
constexpr int   F0_   = 1876;
constexpr int   F0P_  = 1880;     // padded i-count (pads hit zero W rows)
constexpr int   F1_   = 1024;
constexpr int   F2_   = 10;
constexpr int   NT_   = 151;
constexpr float DT_   = 0.02f;
constexpr int   NB1_  = 51;       // bins 0..50

// workspace layout (bytes)
constexpr size_t OFF_W1T  = 0;                       // 1920*1024*4 = 7,864,320
constexpr size_t OFF_REC  = 7864320;                 // 64*1880*8   =   962,560
constexpr size_t OFF_IDX1 = OFF_REC + 962560;        // 64*1024 u8  =    65,536

// ---------------------------------------------------------------------------
// k_prep: fused
//   (a) blocks 0..479:  W1[j][i] -> W1T[i][j] (1920 x 1024), rows >=1876 = 0
//   (b) blocks 480..543: per-(b,i) records {k*256, ti_bits}, k = clamp(
//       ceil(ti*50), 0, 50); i in [1876,1880) -> {50*256, 0} (zero-W rows).
// ---------------------------------------------------------------------------
__global__ __launch_bounds__(256) void k_prep(const float* __restrict__ W1,
                                              const float* __restrict__ ti,
                                              float* __restrict__ W1T,
                                              uint2* __restrict__ krec) {
  const int t = threadIdx.x;
  if (blockIdx.x < 480) {
    __shared__ float tile[64][65];
    const int bx = blockIdx.x;
    const int i0 = (bx % 30) * 64;     // rows 0..1919
    const int j0 = (bx / 30) * 64;
    const int c = t & 63, r4 = t >> 6;
    for (int jj = r4; jj < 64; jj += 4) {
      int i = i0 + c;
      tile[c][jj] = (i < F0_) ? W1[(size_t)(j0 + jj) * F0_ + i] : 0.0f;
    }
    __syncthreads();
    for (int ii = r4; ii < 64; ii += 4) {
      int i = i0 + ii;                 // always < 1920: write zeros for pads
      W1T[(size_t)i * F1_ + j0 + c] = tile[ii][c];
    }
  } else {
    const int b = blockIdx.x - 480;
    const float* tib = ti + (size_t)b * F0_;
    uint2* out = krec + (size_t)b * F0P_;
    for (int i = t; i < F0P_; i += 256) {
      if (i < F0_) {
        float v = tib[i];
        int k = (int)ceilf(v * 50.0f);
        k = k < 0 ? 0 : (k > 50 ? 50 : k);
        out[i] = make_uint2((uint32_t)k << 8, __float_as_uint(v));
      } else {
        out[i] = make_uint2(50u << 8, 0u);   // zero-weight pad row
      }
    }
  }
}

// ---------------------------------------------------------------------------
// Layer-1 main: 1024 one-wave blocks = b*16 + jc (b major, jc minor -> each
// XCD touches 2 W-slices + records ~ 2 MB, L2-resident).  lane = j within the
// 64-col chunk.  Stream i IN ORDER: record {k*256, ti} via uniform-address
// broadcast load, W via coalesced 256 B load — NO data-dependent addresses
// anywhere (r5-r10: hipcc never pipelines gathers; pure streams it can).
// Accumulate ds_add_f32 into bins[2][51][64]: each cell has exactly ONE
// writer lane in program order -> bit-deterministic plain f32 (round-0 math,
// absmax 0.0).  Phase 2: 151-step prefix scan, first crossing, min(.,150).
// ---------------------------------------------------------------------------
__global__ __launch_bounds__(64) void k_main1(const uint2* __restrict__ krec,
                                              const float* __restrict__ W1T,
                                              uint8_t* __restrict__ idx1) {
  __shared__ float bins[2][NB1_][64];   // 26112 B; SC half at byte +13056
  const int blk  = blockIdx.x;          // 1024
  const int b    = blk >> 4;
  const int jc   = blk & 15;
  const int lane = threadIdx.x;

  {
    float4* p = (float4*)(&bins[0][0][0]);
    for (int s = lane; s < (2 * NB1_ * 64) / 4; s += 64)
      p[s] = make_float4(0.f, 0.f, 0.f, 0.f);
  }
  __syncthreads();

  const uint2* __restrict__ rb = krec + (size_t)b * F0P_;
  const float* __restrict__ wb = W1T + (jc << 6) + lane;   // row stride 1024
  char* const base = (char*)(&bins[0][0][0]) + (lane << 2);

#pragma unroll 4
  for (int i = 0; i < F0P_; ++i) {
    uint2 r  = rb[i];                        // uniform addr -> broadcast
    float w  = wb[(size_t)i << 10];          // coalesced 256 B per wave
    float tv = __uint_as_float(r.y);
    float* cell = (float*)(base + r.x);
    atomicAdd(cell, w);                      // ds_add_f32, single-writer cell
    atomicAdd((float*)((char*)cell + 13056), w * tv);
  }

  __syncthreads();

  // phase 2: prefix over bins, first crossing
  float SA = 0.f, SC = 0.f;
  int cnd = NT_;
#pragma unroll 1
  for (int tt = 0; tt < NT_; ++tt) {
    if (tt < NB1_) {
      SA += bins[0][tt][lane];
      SC += bins[1][tt][lane];
    }
    float mv = (float)tt * DT_ * SA - SC;
    if (cnd == NT_ && mv >= 1.0f) cnd = tt;
  }
  cnd = min(cnd, NT_ - 1);                   // forced spike at last timestep
  idx1[((size_t)b << 10) + (jc << 6) + lane] = (uint8_t)cnd;
}

// ---------------------------------------------------------------------------
// Layer-2: brute force. Block = (b,j), 4 waves split the i-range; lane = t.
// ---------------------------------------------------------------------------
__global__ __launch_bounds__(256) void k_main2(const uint8_t* __restrict__ idx1,
                                               const float* __restrict__ W2,
                                               float* __restrict__ out) {
  __shared__ float wrow[F1_];
  __shared__ float tirow[F1_];
  __shared__ float part[4][3][64];
  const int blk = blockIdx.x;          // 640
  const int b   = blk / 10;
  const int j   = blk - b * 10;
  const int tid = threadIdx.x;
  const int lane = tid & 63, wvv = tid >> 6;

  const float*   w = W2  + (size_t)j * F1_;
  const uint8_t* h = idx1 + (size_t)b * F1_;
  for (int s = tid; s < F1_; s += 256) {
    wrow[s]  = w[s];
    tirow[s] = (float)h[s] * DT_;
  }
  __syncthreads();

  const float tl0 = (float)lane * DT_;
  const float tl1 = (float)(lane + 64) * DT_;
  const float tl2 = (float)(lane + 128) * DT_;
  float m0 = 0.f, m1 = 0.f, m2 = 0.f;
  const int i0 = wvv * 256;
#pragma unroll 4
  for (int i = i0; i < i0 + 256; ++i) {
    float tiv = tirow[i], ww = wrow[i];
    m0 = fmaf(ww, fmaxf(tl0 - tiv, 0.f), m0);
    m1 = fmaf(ww, fmaxf(tl1 - tiv, 0.f), m1);
    m2 = fmaf(ww, fmaxf(tl2 - tiv, 0.f), m2);
  }
  part[wvv][0][lane] = m0;
  part[wvv][1][lane] = m1;
  part[wvv][2][lane] = m2;
  __syncthreads();

  if (wvv == 0) {
    m0 = part[0][0][lane] + part[1][0][lane] + part[2][0][lane] + part[3][0][lane];
    m1 = part[0][1][lane] + part[1][1][lane] + part[2][1][lane] + part[3][1][lane];
    m2 = part[0][2][lane] + part[1][2][lane] + part[2][2][lane] + part[3][2][lane];
    unsigned long long b0 = __ballot(m0 >= 1.0f);
    unsigned long long b1 = __ballot(m1 >= 1.0f);
    unsigned long long b2 = __ballot(m2 >= 1.0f);
    b2 &= (1ull << 23) - 1;            // t <= 150
    b2 |= (1ull << 22);                // forced spike at t = 150
    int tres;
    if (b0)      tres = __ffsll((long long)b0) - 1;
    else if (b1) tres = 64 + __ffsll((long long)b1) - 1;
    else         tres = 128 + __ffsll((long long)b2) - 1;
    if (lane == 0) out[(size_t)b * F2_ + j] = (float)tres * DT_;
  }
}

}  // namespace

// ---------------------------------------------------------------------------
extern "C" void kernel_launch(void* const* d_in, const int* in_sizes, int n_in,
                              void* d_out, int out_size, void* d_ws, size_t ws_size,
                              hipStream_t stream) {
  const float* ti = (const float*)d_in[0];   // [64][1876]
  const float* W1 = (const float*)d_in[1];   // [1024][1876]
  const float* W2 = (const float*)d_in[2];   // [10][1024]
  float* out = (float*)d_out;                // [64][10]

  char* ws = (char*)d_ws;
  float*   W1T  = (float*)(ws + OFF_W1T);
  uint2*   krec = (uint2*)(ws + OFF_REC);
  uint8_t* idx1 = (uint8_t*)(ws + OFF_IDX1);

  hipLaunchKernelGGL(k_prep,  dim3(544),  dim3(256), 0, stream, W1, ti, W1T, krec);
  hipLaunchKernelGGL(k_main1, dim3(1024), dim3(64),  0, stream, krec, W1T, idx1);
  hipLaunchKernelGGL(k_main2, dim3(640),  dim3(256), 0, stream, idx1, W2, out);
}

// Round 12
// 107.987 us; speedup vs baseline: 11.6244x; 11.6244x over previous
//
#include <hip/hip_runtime.h>
#include <stdint.h>

namespace {

constexpr int   B_   = 64;
constexpr int   F0_  = 1876;
constexpr int   F1_  = 1024;
constexpr int   F2_  = 10;
constexpr int   NT_  = 151;
constexpr float DT_  = 0.02f;
constexpr float SCL_  = 1073741824.0f;      // 2^30 fixed-point scale
constexpr float ISCL_ = 1.0f / 1073741824.0f;

// ---------------------------------------------------------------------------
// Layer 1, fully fused (no transpose, no sort, no prep):
// 4096 blocks = b*64 + jg  (XCD = jg%8 -> ~1.4 MB/XCD working set, L2-fit),
// 1024 threads = 16 waves; wave wv owns j = jg*16 + wv; lane streams i.
// All loads induction-addressed & coalesced (W1 row-major directly; ti row
// L1-broadcast across the block's waves) — no data-dependent gathers, the
// structural fix for r5-r10's unpipelinable load chains.  Scatter: per-elem
// INT fixed-point ds_add_u32 (r0/r11 proved f32 LDS atomicAdd is a CAS-loop
// disaster ~1240us; int atomics are native) into 4 lane-sub-copies to cut
// same-address multiplicity; k stride 4 B spreads banks.  Deterministic:
// integer adds are order-independent.  Phase 2: collapse copies, 64-lane
// shfl_up inclusive scan over bins, 3-ballot first-crossing (k_main2 trick).
// ---------------------------------------------------------------------------
__global__ __launch_bounds__(1024, 8) void k_main1(const float* __restrict__ ti,
                                                   const float* __restrict__ W1,
                                                   uint8_t* __restrict__ idx1) {
  __shared__ int binA[4][16][52];     // [copy][j_local][bin] 13312 B
  __shared__ int binC[4][16][52];     // 13312 B
  const int blk  = blockIdx.x;        // 4096
  const int b    = blk >> 6;
  const int jg   = blk & 63;
  const int tid  = threadIdx.x;
  const int lane = tid & 63;
  const int wv   = tid >> 6;          // j_local 0..15

  {
    int4* p = (int4*)(&binA[0][0][0]);
    for (int s = tid; s < (2 * 4 * 16 * 52) / 4; s += 1024)
      p[s] = make_int4(0, 0, 0, 0);
  }
  __syncthreads();

  const int j = (jg << 4) + wv;
  const float* __restrict__ wrow = W1 + (size_t)j * F0_;
  const float* __restrict__ tib  = ti + (size_t)b * F0_;
  int* const cA = &binA[lane >> 4][wv][0];
  int* const cC = &binC[lane >> 4][wv][0];

#pragma unroll 4
  for (int it = 0; it < 29; ++it) {           // i = 0 .. 1855
    const int i = (it << 6) + lane;
    float w  = wrow[i];                       // coalesced 256 B, L2-resident
    float tv = tib[i];                        // L1-broadcast across waves
    int k = (int)fminf(ceilf(tv * 50.0f), 50.0f);
    atomicAdd(cA + k, __float2int_rn(w * SCL_));
    atomicAdd(cC + k, __float2int_rn(w * tv * SCL_));
  }
  {                                           // tail i = 1856 .. 1875
    const int i = 1856 + lane;
    if (i < F0_) {
      float w  = wrow[i];
      float tv = tib[i];
      int k = (int)fminf(ceilf(tv * 50.0f), 50.0f);
      atomicAdd(cA + k, __float2int_rn(w * SCL_));
      atomicAdd(cC + k, __float2int_rn(w * tv * SCL_));
    }
  }
  __syncthreads();

  // phase 2: per wave (own j).  lane<51 holds bin 'lane'; inclusive scan
  // over lanes gives SA(t=lane), SC(t=lane); lanes >50 hold the total.
  float sa = 0.f, sc = 0.f;
  if (lane < 51) {
    int a = binA[0][wv][lane] + binA[1][wv][lane] +
            binA[2][wv][lane] + binA[3][wv][lane];
    int c = binC[0][wv][lane] + binC[1][wv][lane] +
            binC[2][wv][lane] + binC[3][wv][lane];
    sa = (float)a * ISCL_;
    sc = (float)c * ISCL_;
  }
#pragma unroll
  for (int d = 1; d < 64; d <<= 1) {
    float s2 = __shfl_up(sa, d);
    float c2 = __shfl_up(sc, d);
    if (lane >= d) { sa += s2; sc += c2; }
  }
  const float saT = __shfl(sa, 63);           // total (lanes 51..63 added 0)
  const float scT = __shfl(sc, 63);
  float m0 = (float)lane * DT_ * sa - sc;             // t = lane (prefix)
  float m1 = (float)(lane + 64) * DT_ * saT - scT;    // t = lane+64 (total)
  float m2 = (float)(lane + 128) * DT_ * saT - scT;   // t = lane+128
  unsigned long long b0 = __ballot(m0 >= 1.0f);
  unsigned long long b1 = __ballot(m1 >= 1.0f);
  unsigned long long b2 = __ballot(m2 >= 1.0f);
  b2 &= (1ull << 23) - 1;                     // t <= 150
  b2 |= (1ull << 22);                         // forced spike at t = 150
  int idx;
  if (b0)      idx = __ffsll((long long)b0) - 1;
  else if (b1) idx = 64 + __ffsll((long long)b1) - 1;
  else         idx = 128 + __ffsll((long long)b2) - 1;
  if (lane == 0) idx1[((size_t)b << 10) + j] = (uint8_t)idx;
}

// ---------------------------------------------------------------------------
// Layer-2: brute force. Block = (b,j), 4 waves split the i-range; lane = t.
// (unchanged, proven)
// ---------------------------------------------------------------------------
__global__ __launch_bounds__(256) void k_main2(const uint8_t* __restrict__ idx1,
                                               const float* __restrict__ W2,
                                               float* __restrict__ out) {
  __shared__ float wrow[F1_];
  __shared__ float tirow[F1_];
  __shared__ float part[4][3][64];
  const int blk = blockIdx.x;          // 640
  const int b   = blk / 10;
  const int j   = blk - b * 10;
  const int tid = threadIdx.x;
  const int lane = tid & 63, wvv = tid >> 6;

  const float*   w = W2  + (size_t)j * F1_;
  const uint8_t* h = idx1 + (size_t)b * F1_;
  for (int s = tid; s < F1_; s += 256) {
    wrow[s]  = w[s];
    tirow[s] = (float)h[s] * DT_;
  }
  __syncthreads();

  const float tl0 = (float)lane * DT_;
  const float tl1 = (float)(lane + 64) * DT_;
  const float tl2 = (float)(lane + 128) * DT_;
  float m0 = 0.f, m1 = 0.f, m2 = 0.f;
  const int i0 = wvv * 256;
#pragma unroll 4
  for (int i = i0; i < i0 + 256; ++i) {
    float tiv = tirow[i], ww = wrow[i];
    m0 = fmaf(ww, fmaxf(tl0 - tiv, 0.f), m0);
    m1 = fmaf(ww, fmaxf(tl1 - tiv, 0.f), m1);
    m2 = fmaf(ww, fmaxf(tl2 - tiv, 0.f), m2);
  }
  part[wvv][0][lane] = m0;
  part[wvv][1][lane] = m1;
  part[wvv][2][lane] = m2;
  __syncthreads();

  if (wvv == 0) {
    m0 = part[0][0][lane] + part[1][0][lane] + part[2][0][lane] + part[3][0][lane];
    m1 = part[0][1][lane] + part[1][1][lane] + part[2][1][lane] + part[3][1][lane];
    m2 = part[0][2][lane] + part[1][2][lane] + part[2][2][lane] + part[3][2][lane];
    unsigned long long b0 = __ballot(m0 >= 1.0f);
    unsigned long long b1 = __ballot(m1 >= 1.0f);
    unsigned long long b2 = __ballot(m2 >= 1.0f);
    b2 &= (1ull << 23) - 1;            // t <= 150
    b2 |= (1ull << 22);                // forced spike at t = 150
    int tres;
    if (b0)      tres = __ffsll((long long)b0) - 1;
    else if (b1) tres = 64 + __ffsll((long long)b1) - 1;
    else         tres = 128 + __ffsll((long long)b2) - 1;
    if (lane == 0) out[(size_t)b * F2_ + j] = (float)tres * DT_;
  }
}

}  // namespace

// ---------------------------------------------------------------------------
extern "C" void kernel_launch(void* const* d_in, const int* in_sizes, int n_in,
                              void* d_out, int out_size, void* d_ws, size_t ws_size,
                              hipStream_t stream) {
  const float* ti = (const float*)d_in[0];   // [64][1876]
  const float* W1 = (const float*)d_in[1];   // [1024][1876]
  const float* W2 = (const float*)d_in[2];   // [10][1024]
  float* out = (float*)d_out;                // [64][10]

  uint8_t* idx1 = (uint8_t*)d_ws;            // 64*1024 u8 = 65,536 B

  hipLaunchKernelGGL(k_main1, dim3(4096), dim3(1024), 0, stream, ti, W1, idx1);
  hipLaunchKernelGGL(k_main2, dim3(640),  dim3(256),  0, stream, idx1, W2, out);
}